// Round 3
// baseline (363.566 us; speedup 1.0000x reference)
//
#include <hip/hip_runtime.h>
#include <math.h>

#define IMG 512
#define PLANES 96            // 32 N * 3 C
#define XS_W 54              // valid output columns per wave
#define NXS 10               // ceil(512/54)
#define YS_H 64              // output rows per wave
#define NYS 8                // 512/64
#define WPB 4                // waves per block
#define NSLOT 32
#define ACC_STRIDE 16        // doubles per atomic slot (128 B pad)
#define INV_NPIX (1.0 / 25165824.0)

// Full-wave lane shifts via DPP (no LDS/DS pipe). If shl/shr semantics are
// mirrored vs expectation it is harmless: the Gaussian window is symmetric,
// so a mirrored window produces identical H sums. bound_ctrl=1 zero-fills
// wave-edge lanes, which only feed outputs discarded by out_ok.
__device__ __forceinline__ float wshr1(float v) {
    return __int_as_float(__builtin_amdgcn_update_dpp(0, __float_as_int(v), 0x138, 0xF, 0xF, true));
}
__device__ __forceinline__ float wshl1(float v) {
    return __int_as_float(__builtin_amdgcn_update_dpp(0, __float_as_int(v), 0x130, 0xF, 0xF, true));
}

template<int P>
__device__ __forceinline__ void row_step(
    int T, int y0, bool col_ok, int colc,
    const float* __restrict__ p1, const float* __restrict__ p2,
    float& x1, float& x2, float& y1, float& y2,
    const float (&g)[11], float (&A)[5][11],
    bool out_ok, float& sL, float& sC, float& sS)
{
    const int t = T + P;
    // ---- depth-2 prefetch: row t+2 (row index & bounds are wave-uniform -> SALU) ----
    float f1 = 0.f, f2 = 0.f;
    {
        const int gy = y0 - 3 + t;               // (y0-5) + (t+2)
        if ((unsigned)gy < IMG) {                // uniform branch: edge rows skip loads
            float l1 = (p1 + gy * IMG)[colc];    // colc clamped -> always in-bounds
            float l2 = (p2 + gy * IMG)[colc];
            f1 = col_ok ? l1 : 0.f;
            f2 = col_ok ? l2 : 0.f;
        }
    }
    // ---- horizontal window via DPP wave shifts (4 independent 5-deep chains) ----
    float a[11], b[11];
    a[5] = x1; b[5] = x2;
    a[6] = wshr1(a[5]);  a[7] = wshr1(a[6]);  a[8] = wshr1(a[7]);  a[9] = wshr1(a[8]);  a[10] = wshr1(a[9]);
    a[4] = wshl1(a[5]);  a[3] = wshl1(a[4]);  a[2] = wshl1(a[3]);  a[1] = wshl1(a[2]);  a[0]  = wshl1(a[1]);
    b[6] = wshr1(b[5]);  b[7] = wshr1(b[6]);  b[8] = wshr1(b[7]);  b[9] = wshr1(b[8]);  b[10] = wshr1(b[9]);
    b[4] = wshl1(b[5]);  b[3] = wshl1(b[4]);  b[2] = wshl1(b[3]);  b[1] = wshl1(b[2]);  b[0]  = wshl1(b[1]);
    // ---- horizontal 11-tap for 5 quantities (weights in SGPRs) ----
    float H1 = 0.f, H2 = 0.f, H11 = 0.f, H22 = 0.f, H12 = 0.f;
    #pragma unroll
    for (int j = 0; j < 11; ++j) {
        float w = g[j];
        float t1 = w * a[j], t2 = w * b[j];
        H1 += t1; H2 += t2;
        H11 = fmaf(t1, a[j], H11);
        H22 = fmaf(t2, b[j], H22);
        H12 = fmaf(t1, b[j], H12);
    }
    // ---- vertical ring accumulate (statically indexed: t ≡ P mod 11) ----
    #pragma unroll
    for (int j = 0; j < 11; ++j) {
        const int s = (P + j + 1) % 11;
        float w = g[10 - j];
        A[0][s] = fmaf(w, H1,  A[0][s]);
        A[1][s] = fmaf(w, H2,  A[1][s]);
        A[2][s] = fmaf(w, H11, A[2][s]);
        A[3][s] = fmaf(w, H22, A[3][s]);
        A[4][s] = fmaf(w, H12, A[4][s]);
    }
    // ---- emit output row r = t-10 ----
    const int es = (P + 1) % 11;
    if (t >= 10) {                               // wave-uniform (t <= 73 by loop bound)
        float mu1 = A[0][es], mu2 = A[1][es];
        float x11 = A[2][es], x22 = A[3][es], x12 = A[4][es];
        float mu1s = mu1 * mu1, mu2s = mu2 * mu2, mu12 = mu1 * mu2;
        float v1 = x11 - mu1s, v2 = x22 - mu2s, v12 = x12 - mu12;
        float a1 = fabsf(v1), a2 = fabsf(v2);
        float q12 = sqrtf(a1 * a2);
        const float C1 = 1e-4f, C2 = 9e-4f, C3 = 4.5e-4f;
        float eL = __fdividef(2.f * mu12 + C1, mu1s + mu2s + C1);
        float eC = __fdividef(2.f * q12 + C2, a1 + a2 + C2);
        float eS = __fdividef(v12 + C3, q12 + C3);
        if (out_ok) { sL += eL; sC += eC; sS += eS; }
    }
    #pragma unroll
    for (int q = 0; q < 5; ++q) A[q][es] = 0.f;
    x1 = y1; x2 = y2; y1 = f1; y2 = f2;
}

__global__ __launch_bounds__(256, 4) void ssim_main(
    const float* __restrict__ img1, const float* __restrict__ img2,
    const float* __restrict__ win, double* __restrict__ acc)
{
    const int lane = threadIdx.x & 63;
    // force wave-uniform values into SGPRs so plane/strip/row math is SALU
    const int wid  = __builtin_amdgcn_readfirstlane(blockIdx.x * WPB + (threadIdx.x >> 6));
    const int plane = wid / (NXS * NYS);
    const int rem   = wid % (NXS * NYS);
    const int ys = rem / NXS, xs = rem % NXS;
    const int x0 = xs * XS_W;
    const int y0 = ys * YS_H;
    const int col = x0 - 5 + lane;
    const bool col_ok = (unsigned)col < IMG;
    const int colc = min(max(col, 0), IMG - 1);  // clamped: safe address even when masked
    const bool out_ok = (lane >= 5) && (lane <= 58) && col_ok;

    // separable 1-D Gaussian from diagonal of 2-D window: w2d[i][i]=g[i]^2.
    // readfirstlane -> SGPRs (keeps VGPR pressure down; VOP3 takes 1 SGPR operand)
    float g[11];
    #pragma unroll
    for (int j = 0; j < 11; ++j)
        g[j] = __int_as_float(__builtin_amdgcn_readfirstlane(__float_as_int(sqrtf(win[j * 12]))));

    const float* p1 = img1 + (size_t)plane * (IMG * IMG);
    const float* p2 = img2 + (size_t)plane * (IMG * IMG);

    // startup: rows t=0 (gy=y0-5) and t=1 (gy=y0-4)
    float x1 = 0.f, x2 = 0.f, y1 = 0.f, y2 = 0.f;
    {
        int gy = y0 - 5;
        if ((unsigned)gy < IMG) {
            float l1 = (p1 + gy * IMG)[colc], l2 = (p2 + gy * IMG)[colc];
            x1 = col_ok ? l1 : 0.f; x2 = col_ok ? l2 : 0.f;
        }
    }
    {
        int gy = y0 - 4;
        if ((unsigned)gy < IMG) {
            float l1 = (p1 + gy * IMG)[colc], l2 = (p2 + gy * IMG)[colc];
            y1 = col_ok ? l1 : 0.f; y2 = col_ok ? l2 : 0.f;
        }
    }

    float A[5][11];
    #pragma unroll
    for (int q = 0; q < 5; ++q)
        #pragma unroll
        for (int s = 0; s < 11; ++s) A[q][s] = 0.f;

    float sL = 0.f, sC = 0.f, sS = 0.f;

    #pragma unroll 1
    for (int T = 0; T < 66; T += 11) {           // t = 0..65
        row_step<0>(T, y0, col_ok, colc, p1, p2, x1, x2, y1, y2, g, A, out_ok, sL, sC, sS);
        row_step<1>(T, y0, col_ok, colc, p1, p2, x1, x2, y1, y2, g, A, out_ok, sL, sC, sS);
        row_step<2>(T, y0, col_ok, colc, p1, p2, x1, x2, y1, y2, g, A, out_ok, sL, sC, sS);
        row_step<3>(T, y0, col_ok, colc, p1, p2, x1, x2, y1, y2, g, A, out_ok, sL, sC, sS);
        row_step<4>(T, y0, col_ok, colc, p1, p2, x1, x2, y1, y2, g, A, out_ok, sL, sC, sS);
        row_step<5>(T, y0, col_ok, colc, p1, p2, x1, x2, y1, y2, g, A, out_ok, sL, sC, sS);
        row_step<6>(T, y0, col_ok, colc, p1, p2, x1, x2, y1, y2, g, A, out_ok, sL, sC, sS);
        row_step<7>(T, y0, col_ok, colc, p1, p2, x1, x2, y1, y2, g, A, out_ok, sL, sC, sS);
        row_step<8>(T, y0, col_ok, colc, p1, p2, x1, x2, y1, y2, g, A, out_ok, sL, sC, sS);
        row_step<9>(T, y0, col_ok, colc, p1, p2, x1, x2, y1, y2, g, A, out_ok, sL, sC, sS);
        row_step<10>(T, y0, col_ok, colc, p1, p2, x1, x2, y1, y2, g, A, out_ok, sL, sC, sS);
    }
    // tail: t = 66..73
    row_step<0>(66, y0, col_ok, colc, p1, p2, x1, x2, y1, y2, g, A, out_ok, sL, sC, sS);
    row_step<1>(66, y0, col_ok, colc, p1, p2, x1, x2, y1, y2, g, A, out_ok, sL, sC, sS);
    row_step<2>(66, y0, col_ok, colc, p1, p2, x1, x2, y1, y2, g, A, out_ok, sL, sC, sS);
    row_step<3>(66, y0, col_ok, colc, p1, p2, x1, x2, y1, y2, g, A, out_ok, sL, sC, sS);
    row_step<4>(66, y0, col_ok, colc, p1, p2, x1, x2, y1, y2, g, A, out_ok, sL, sC, sS);
    row_step<5>(66, y0, col_ok, colc, p1, p2, x1, x2, y1, y2, g, A, out_ok, sL, sC, sS);
    row_step<6>(66, y0, col_ok, colc, p1, p2, x1, x2, y1, y2, g, A, out_ok, sL, sC, sS);
    row_step<7>(66, y0, col_ok, colc, p1, p2, x1, x2, y1, y2, g, A, out_ok, sL, sC, sS);

    // ---- wave reduction (no barriers), one diluted atomic set per wave ----
    #pragma unroll
    for (int off = 32; off > 0; off >>= 1) {
        sL += __shfl_down(sL, off, 64);
        sC += __shfl_down(sC, off, 64);
        sS += __shfl_down(sS, off, 64);
    }
    if (lane == 0) {
        double* slot = acc + (size_t)(wid & (NSLOT - 1)) * ACC_STRIDE;
        atomicAdd(slot + 0, (double)sL);
        atomicAdd(slot + 1, (double)sC);
        atomicAdd(slot + 2, (double)sS);
    }
}

__global__ void ssim_fin(const double* __restrict__ acc, float* __restrict__ out) {
    int i = threadIdx.x;
    if (i < 3) {
        double s = 0.0;
        for (int k = 0; k < NSLOT; ++k) s += acc[k * ACC_STRIDE + i];
        out[i] = (float)(s * INV_NPIX);
    }
}

extern "C" void kernel_launch(void* const* d_in, const int* in_sizes, int n_in,
                              void* d_out, int out_size, void* d_ws, size_t ws_size,
                              hipStream_t stream) {
    const float* img1 = (const float*)d_in[0];
    const float* img2 = (const float*)d_in[1];
    const float* win  = (const float*)d_in[2];
    float* out = (float*)d_out;
    double* acc = (double*)d_ws;

    // zero the atomic accumulators (graph-capture-safe; bit pattern 0 == +0.0)
    hipMemsetAsync(d_ws, 0, NSLOT * ACC_STRIDE * sizeof(double), stream);
    ssim_main<<<(PLANES * NXS * NYS) / WPB, 64 * WPB, 0, stream>>>(img1, img2, win, acc);
    ssim_fin<<<1, 64, 0, stream>>>(acc, out);
}